// Round 1
// baseline (1567.135 us; speedup 1.0000x reference)
//
#include <hip/hip_runtime.h>

// Problem constants (from reference):
//   T=26 tables, R=100000 rows, D=128 dim, B=4096 batch, L=20 bag size
//   MODES alternate [SUM, MEAN, SUM, MEAN, ...] -> mode = t & 1
constexpr int T = 26;
constexpr int R = 100000;
constexpr int D = 128;
constexpr int B = 4096;
constexpr int L = 20;

// One 32-lane group per bag. Each lane owns a float4 (4 floats):
// 32 lanes x 16 B = 512 B = one full row per load instruction (coalesced).
// Block = 256 threads = 8 bags. Grid = T*B/8 = 13312 blocks.
__global__ __launch_bounds__(256) void merged_embedding_bag_kernel(
    const float* __restrict__ W,      // [T, R, D]
    const int*   __restrict__ indices, // [T, B, L] (int32)
    float*       __restrict__ out)     // [T, B, D]
{
    const int lane = threadIdx.x & 31;          // float4 slot within row
    const int bag_in_block = threadIdx.x >> 5;  // 0..7
    const int g = blockIdx.x * 8 + bag_in_block; // global bag id in [0, T*B)
    const int t = g >> 12;                      // g / 4096
    const int b = g & 4095;                     // g % 4096

    const int*   idxp = indices + ((size_t)t * B + b) * L;
    const float* wt   = W + (size_t)t * R * D;

    // Prefetch all 20 indices so the row loads can issue back-to-back.
    int idxs[L];
#pragma unroll
    for (int l = 0; l < L; ++l) idxs[l] = idxp[l];

    float4 acc = make_float4(0.f, 0.f, 0.f, 0.f);
#pragma unroll
    for (int l = 0; l < L; ++l) {
        const float4* row = (const float4*)(wt + (size_t)idxs[l] * D);
        float4 v = row[lane];
        acc.x += v.x; acc.y += v.y; acc.z += v.z; acc.w += v.w;
    }

    // MEAN pooling for odd tables, SUM for even.
    const float scale = (t & 1) ? (1.0f / (float)L) : 1.0f;
    acc.x *= scale; acc.y *= scale; acc.z *= scale; acc.w *= scale;

    float4* op = (float4*)(out + ((size_t)t * B + b) * D);
    op[lane] = acc;
}

extern "C" void kernel_launch(void* const* d_in, const int* in_sizes, int n_in,
                              void* d_out, int out_size, void* d_ws, size_t ws_size,
                              hipStream_t stream) {
    const float* W       = (const float*)d_in[0];
    const int*   indices = (const int*)d_in[1];
    float*       out     = (float*)d_out;

    const int bags = T * B;              // 106496
    const int blocks = bags / 8;         // 13312 (exact: 106496 % 8 == 0)
    merged_embedding_bag_kernel<<<blocks, 256, 0, stream>>>(W, indices, out);
}